// Round 12
// baseline (462.730 us; speedup 1.0000x reference)
//
#include <hip/hip_runtime.h>
#include <math.h>

#define NN 50000
#define EE 800000
#define ET (EE + NN)
#define HID 128
#define NSTORE 50
#define NBL 196                      // ceil(NN/256)
#define CNT_B 3125                   // EE/256 edge-count blocks
#define WCV_B 192                    // 3*128*128/256 weight cvt blocks
#define IWC_B 32                     // 128*64/256 inW cvt blocks
#define SCT_B2 1661                  // ceil(ET/512) scatter blocks (512-thread, in gemm2 l0)
#define GEMB2 782                    // ceil(NN/64) gemm tiles (64-row, hoisted-B structure)
#define IPB 782                      // ceil(NN/64) inproj tiles (64-row, latency-sized)
#define SSB 512                      // store-sum partial blocks (2 blocks/CU)

typedef unsigned short ushort_t;
typedef unsigned int u32;
typedef __attribute__((ext_vector_type(8))) short bf8;
typedef __attribute__((ext_vector_type(4))) float f4;
typedef __attribute__((ext_vector_type(2))) float f2;
typedef __attribute__((ext_vector_type(4))) unsigned int u4;

__device__ __forceinline__ ushort_t f2b(float f) {
    union { float f; unsigned int i; } v; v.f = f;
    unsigned int r = (v.i + 0x7fffu + ((v.i >> 16) & 1u)) >> 16;
    return (ushort_t)r;
}
__device__ __forceinline__ f2 b2f2v(unsigned int u) {
    union { unsigned int i; float f; } lo, hi;
    lo.i = u << 16; hi.i = u & 0xffff0000u;
    f2 r; r.x = lo.f; r.y = hi.f; return r;
}
__device__ __forceinline__ unsigned int pk2(float lo, float hi) {
    return (unsigned int)f2b(lo) | ((unsigned int)f2b(hi) << 16);
}
__device__ __forceinline__ f2 max2(f2 a, f2 b) {
#if __has_builtin(__builtin_elementwise_max)
    return __builtin_elementwise_max(a, b);
#else
    f2 r; r.x = fmaxf(a.x, b.x); r.y = fmaxf(a.y, b.y); return r;
#endif
}

// ---------------------------------------------------------------- build: edge count (u32 packed atomic) + weight cvt.
// packed[dst]: bits 24+: degree (<=255); bits 0..23: sum(ew) in 2^-18 fixed
// point (deg<=~50, ew<1 -> sum < 50*2^18 < 2^24: no field overflow).
__global__ __launch_bounds__(256) void k_build(const int* __restrict__ ei, const float* __restrict__ ew,
                                               const float* __restrict__ inW,
                                               const float* __restrict__ gWl, const float* __restrict__ gWr,
                                               ushort_t* __restrict__ inWt,
                                               ushort_t* __restrict__ Wlt, ushort_t* __restrict__ Wrt,
                                               u32* __restrict__ packed, int* __restrict__ rank) {
    int b = blockIdx.x, t = threadIdx.x;
    if (b < CNT_B) {                               // ---- edge count
        int i = b * 256 + t;
        int dst = ei[EE + i];
        unsigned int wfix = __float2uint_rn(ew[i] * 262144.0f);
        unsigned int old = atomicAdd(&packed[dst], (1u << 24) | wfix);
        rank[i] = (int)(old >> 24);
        return;
    }
    if (b < CNT_B + WCV_B) {                       // ---- Wlt[l][n*128+k] = W[l][k*128+n]
        int i = (b - CNT_B) * 256 + t;
        int l = i >> 14, r = i & 16383, nn2 = r >> 7, k = r & 127;
        Wlt[i] = f2b(gWl[(size_t)l * 16384 + k * 128 + nn2]);
        Wrt[i] = f2b(gWr[(size_t)l * 16384 + k * 128 + nn2]);
        return;
    }
    {                                              // ---- inWt[c*64+k] = inW[k*128+c]
        int i = (b - CNT_B - WCV_B) * 256 + t;
        int c = i >> 6, k = i & 63;
        inWt[i] = f2b(inW[k * 128 + c]);
    }
}

// per-256-chunk sums of (deg+1)
__global__ __launch_bounds__(256) void k_psum(const u32* __restrict__ packed, int* __restrict__ bsum) {
    int t = threadIdx.x, bidx = blockIdx.x;
    int i = bidx * 256 + t;
    int v = (i < NN) ? (int)(packed[i] >> 24) + 1 : 0;
#pragma unroll
    for (int d = 1; d < 64; d <<= 1) v += __shfl_xor(v, d);
    __shared__ int ws4[4];
    if ((t & 63) == 0) ws4[t >> 6] = v;
    __syncthreads();
    if (t == 0) bsum[bidx] = ws4[0] + ws4[1] + ws4[2] + ws4[3];
}

// merged scan: each block redundantly sums bsum[0..bid) (196 L2-hot ints), then local scan
__global__ __launch_bounds__(256) void k_offs2(const u32* __restrict__ packed,
                                               const int* __restrict__ bsum, int* __restrict__ offs) {
    __shared__ int bws[4];
    __shared__ int wsum4[4];
    int t = threadIdx.x, bidx = blockIdx.x;
    int i = bidx * 256 + t;
    int v = (i < NN) ? (int)(packed[i] >> 24) + 1 : 0;
    int lane = t & 63, w = t >> 6;

    // block base = sum of bsum[0..bidx)
    int bv = (t < bidx) ? bsum[t] : 0;
#pragma unroll
    for (int d = 1; d < 64; d <<= 1) bv += __shfl_xor(bv, d);
    if (lane == 0) bws[w] = bv;

    // local inclusive scan within wave
    int sc = v;
#pragma unroll
    for (int d = 1; d < 64; d <<= 1) {
        int u = __shfl_up(sc, d);
        if (lane >= d) sc += u;
    }
    if (lane == 63) wsum4[w] = sc;
    __syncthreads();
    int base = bws[0] + bws[1] + bws[2] + bws[3];
    int wo = 0;
    for (int k = 0; k < w; ++k) wo += wsum4[k];
    if (i < NN) offs[i] = base + wo + sc - v;
    if (bidx == 0 && t == 0) offs[NN] = ET;
}

// ---------------------------------------------------------------- input proj: GELU + LN fused, K=64, f32 in (inline bf16 cvt).
// Latency-sized: 64-row tiles x 8 waves (4 row-groups x 2 col-halves).
__global__ __launch_bounds__(512) void k_inproj(const float* __restrict__ X,
                                                const ushort_t* __restrict__ Wt,
                                                const float* __restrict__ bias,
                                                const float* __restrict__ g,
                                                const float* __restrict__ be,
                                                ushort_t* __restrict__ hb) {
    const int K = 64;
    __shared__ float s1[2][64], s2[2][64];
    int t = threadIdx.x;
    int w = t >> 6, lane = t & 63;
    int cw = w & 1, rw = w >> 1;           // rw 0..3: 16-row group; cw: 64-col half
    int q = lane >> 4, l16 = lane & 15;
    int row0 = blockIdx.x * 64 + rw * 16;
    int col0 = cw * 64;
    bf8 z; for (int k = 0; k < 8; ++k) z[k] = 0;

    bf8 bfr[2][4];
#pragma unroll
    for (int kk = 0; kk < 2; ++kk)
#pragma unroll
        for (int j = 0; j < 4; ++j)
            bfr[kk][j] = *(const bf8*)(Wt + (size_t)(col0 + j * 16 + l16) * K + kk * 32 + q * 8);

    f4 acc[4];
#pragma unroll
    for (int j = 0; j < 4; ++j) acc[j] = (f4)(0.f);

#pragma unroll
    for (int kk = 0; kk < 2; ++kk) {
        bf8 af;
        int r = row0 + l16;
        if (r < NN) {
            const float* xp = X + (size_t)r * K + kk * 32 + q * 8;
            f4 a = *(const f4*)xp;
            f4 c = *(const f4*)(xp + 4);
            u4 up; up.x = pk2(a.x, a.y); up.y = pk2(a.z, a.w);
            up.z = pk2(c.x, c.y); up.w = pk2(c.z, c.w);
            af = *(bf8*)&up;
        } else af = z;
#pragma unroll
        for (int j = 0; j < 4; ++j)
            acc[j] = __builtin_amdgcn_mfma_f32_16x16x32_bf16(af, bfr[kk][j], acc[j], 0, 0, 0);
    }
#pragma unroll
    for (int j = 0; j < 4; ++j) {
        float bv = bias[col0 + j * 16 + l16];
#pragma unroll
        for (int r = 0; r < 4; ++r) {
            float v = acc[j][r] + bv;
            v = 0.5f * v * (1.f + erff(v * 0.70710678118654752f));
            acc[j][r] = v;
        }
    }
#pragma unroll
    for (int r = 0; r < 4; ++r) {
        float sm = acc[0][r] + acc[1][r] + acc[2][r] + acc[3][r];
        float sq = acc[0][r] * acc[0][r] + acc[1][r] * acc[1][r]
                 + acc[2][r] * acc[2][r] + acc[3][r] * acc[3][r];
#pragma unroll
        for (int k = 1; k < 16; k <<= 1) { sm += __shfl_xor(sm, k); sq += __shfl_xor(sq, k); }
        if (l16 == 0) {
            int rl = rw * 16 + q * 4 + r;
            s1[cw][rl] = sm; s2[cw][rl] = sq;
        }
    }
    __syncthreads();
#pragma unroll
    for (int r = 0; r < 4; ++r) {
        int rl = rw * 16 + q * 4 + r;
        int gr = blockIdx.x * 64 + rl;
        if (gr >= NN) continue;
        float sm = s1[0][rl] + s1[1][rl];
        float sq = s2[0][rl] + s2[1][rl];
        float mu = sm * (1.f / 128.f);
        float var = sq * (1.f / 128.f) - mu * mu;
        float rinv = rsqrtf(var + 1e-5f);
#pragma unroll
        for (int j = 0; j < 4; ++j) {
            int gc = col0 + j * 16 + l16;
            float v = (acc[j][r] - mu) * rinv * g[gc] + be[gc];
            hb[(size_t)gr * HID + gc] = f2b(v);
        }
    }
}

// ---------------------------------------------------------------- fused dual GEMM (K=128), 64-row tiles WITH the proven
// hoisted-B pipeline: per kk, bfk[4] batched (4 independent L2-hot loads),
// then af[2] from LDS, then 8 MFMA -- round-10's regression interleaved
// B-loads 1:1 with MFMA (serialized); this keeps round-7's load:compute
// shape at half tile height. 782 blocks (3.05/CU) vs 391 (1.5/CU).
// Waves: side(2) x row-half(2) x col-half(2); acc[2][4], 32 MFMA/wave.
// blocks >= GEMB2: CSR scatter (l0). csr.x = BYTE offset of source row.
__global__ __launch_bounds__(512) void k_gemm2(const ushort_t* __restrict__ A,
                                               const ushort_t* __restrict__ Wt0,
                                               const ushort_t* __restrict__ Wt1,
                                               const float* __restrict__ b0,
                                               const float* __restrict__ b1,
                                               ushort_t* __restrict__ o0,
                                               ushort_t* __restrict__ o1, int n,
                                               const int* __restrict__ ei,
                                               const float* __restrict__ ew,
                                               const int* __restrict__ offs,
                                               const u32* __restrict__ packed,
                                               const int* __restrict__ rank,
                                               int2* __restrict__ csr) {
    int bid = blockIdx.x;
    if (bid >= GEMB2) {                            // ---- CSR scatter
        int i = (bid - GEMB2) * 512 + threadIdx.x;
        if (i < EE) {
            int src = ei[i], dst = ei[EE + i];
            int pos = offs[dst] + rank[i];
            int2 v; v.x = src << 8; v.y = __float_as_int(ew[i]);
            csr[pos] = v;
        } else if (i < ET) {
            int nd = i - EE;
            u32 p = packed[nd];
            int deg = (int)(p >> 24);
            float wsf = (float)(p & 0xFFFFFFu) * (1.0f / 262144.0f);
            float la = wsf / fmaxf((float)deg, 1.0f);
            int pos = offs[nd + 1] - 1;
            int2 v; v.x = nd << 8; v.y = __float_as_int(la);
            csr[pos] = v;
        }
        return;
    }
    const int K = 128;
    __shared__ char As[64 * 256];                // 16 KB, XOR-swizzled rows
    int t = threadIdx.x;
    int row0 = bid * 64;
    bf8 z; for (int k = 0; k < 8; ++k) z[k] = 0;

    {   // stage A: 8 threads/row, 32 B each (round-10 layout, correctness-proven)
        int row = t >> 3, cq = t & 7;
        const ushort_t* srcp = A + (size_t)(row0 + row) * K + cq * 16;
        int swz = (row & 7) << 4;
        char* dst = As + row * 256;
        bool ok = (row0 + row) < n;
#pragma unroll
        for (int k = 0; k < 2; ++k) {
            bf8 v = ok ? *(const bf8*)(srcp + k * 8) : z;
            *(bf8*)(dst + ((cq * 32 + k * 16) ^ swz)) = v;
        }
    }
    __syncthreads();

    int w = t >> 6, lane = t & 63;
    int side = w >> 2, rw = (w >> 1) & 1, cw = w & 1;
    const ushort_t* Wt = side ? Wt1 : Wt0;
    const float* bias = side ? b1 : b0;
    ushort_t* outb = side ? o1 : o0;
    int q = lane >> 4, l16 = lane & 15;
    int col0 = cw * 64;

    f4 acc[2][4];
#pragma unroll
    for (int i = 0; i < 2; ++i)
#pragma unroll
        for (int j = 0; j < 4; ++j) acc[i][j] = (f4)(0.f);

#pragma unroll
    for (int kk = 0; kk < 4; ++kk) {
        bf8 bfk[4];
#pragma unroll
        for (int j = 0; j < 4; ++j)
            bfk[j] = *(const bf8*)(Wt + (size_t)(col0 + j * 16 + l16) * K + kk * 32 + q * 8);
        bf8 af[2];
#pragma unroll
        for (int i = 0; i < 2; ++i) {
            int r = rw * 32 + i * 16 + l16;
            af[i] = *(const bf8*)(As + r * 256 + ((kk * 64 + q * 16) ^ ((r & 7) << 4)));
        }
#pragma unroll
        for (int i = 0; i < 2; ++i)
#pragma unroll
            for (int j = 0; j < 4; ++j)
                acc[i][j] = __builtin_amdgcn_mfma_f32_16x16x32_bf16(af[i], bfk[j], acc[i][j], 0, 0, 0);
    }
#pragma unroll
    for (int i = 0; i < 2; ++i) {
        int gr0 = row0 + rw * 32 + i * 16 + q * 4;
#pragma unroll
        for (int j = 0; j < 4; ++j) {
            int gc = col0 + j * 16 + l16;
            float bv = bias[gc];
#pragma unroll
            for (int r = 0; r < 4; ++r) {
                int gr = gr0 + r;
                if (gr < n) outb[(size_t)gr * HID + gc] = f2b(acc[i][j][r] + bv);
            }
        }
    }
}

// ---------------------------------------------------------------- GATv2 attention (round-1 form: VGPR 36, ~59% occ -- the
// proven floor across 7 structural variants; pattern-limited at ~2.7 TB/s
// on the L2-miss path).
__global__ __launch_bounds__(256) void k_attn(const ushort_t* __restrict__ xl,
                                              const ushort_t* __restrict__ xr,
                                              ushort_t* __restrict__ hb,
                                              const int* __restrict__ offs,
                                              const int2* __restrict__ csr,
                                              const float* __restrict__ We,
                                              const float* __restrict__ att,
                                              const float* __restrict__ gbias,
                                              const float* __restrict__ g,
                                              const float* __restrict__ b) {
    int wid = (blockIdx.x * 256 + threadIdx.x) >> 6;
    int lane = threadIdx.x & 63;
    if (wid >= NN) return;
    int hd = lane & 15;          // head index (16 heads; DH=8 in-lane)
    int grp = lane >> 4;         // edge subgroup 0..3
    int dbase = hd * 8;
    int db2 = hd * 16;           // byte offset of this head's 8 bf16 within a row
    size_t base = (size_t)wid * HID;

    f2 xr2[4], at2[4], we2[4];
    {
        u4 uxr = *(const u4*)(xr + base + dbase);
        xr2[0] = b2f2v(uxr.x); xr2[1] = b2f2v(uxr.y);
        xr2[2] = b2f2v(uxr.z); xr2[3] = b2f2v(uxr.w);
        f4 a0 = *(const f4*)(att + dbase), a1 = *(const f4*)(att + dbase + 4);
        at2[0].x = a0.x; at2[0].y = a0.y; at2[1].x = a0.z; at2[1].y = a0.w;
        at2[2].x = a1.x; at2[2].y = a1.y; at2[3].x = a1.z; at2[3].y = a1.w;
        f4 w0 = *(const f4*)(We + dbase), w1 = *(const f4*)(We + dbase + 4);
        we2[0].x = w0.x; we2[0].y = w0.y; we2[1].x = w0.z; we2[1].y = w0.w;
        we2[2].x = w1.x; we2[2].y = w1.y; we2[3].x = w1.z; we2[3].y = w1.w;
    }
    int p0 = offs[wid], p1 = offs[wid + 1];
    float Z = 0.f;
    f2 acc2[4];
#pragma unroll
    for (int q = 0; q < 4; ++q) { acc2[q].x = 0.f; acc2[q].y = 0.f; }

    // issue csr record load (16-lane same-address broadcast) + row gather
#define LOADQ(UX, EA, VM)                                                      \
    {                                                                          \
        int ei_ = e + grp;                                                     \
        VM = (ei_ < p1);                                                       \
        int2 m2_ = csr[VM ? ei_ : (p1 - 1)];                                   \
        EA = __int_as_float(m2_.y);                                            \
        UX = *(const u4*)((const char*)xl + (unsigned)m2_.x + db2);            \
    }

#define COMPQ(UX, EA, VM)                                                      \
    {                                                                          \
        f2 x2_[4];                                                             \
        x2_[0] = b2f2v(UX.x); x2_[1] = b2f2v(UX.y);                            \
        x2_[2] = b2f2v(UX.z); x2_[3] = b2f2v(UX.w);                            \
        f2 lg2_; lg2_.x = 0.f; lg2_.y = 0.f;                                   \
        _Pragma("unroll")                                                      \
        for (int q_ = 0; q_ < 4; ++q_) {                                       \
            f2 t_ = (x2_[q_] + xr2[q_]) + EA * we2[q_];                        \
            t_ = max2(t_, t_ * 0.2f);                                          \
            lg2_ += at2[q_] * t_;                                              \
        }                                                                      \
        float w_ = VM ? __expf(lg2_.x + lg2_.y) : 0.f;                         \
        Z += w_;                                                               \
        _Pragma("unroll")                                                      \
        for (int q_ = 0; q_ < 4; ++q_) acc2[q_] += w_ * x2_[q_];               \
    }

    {
        u4 uxA, uxB; float eaA, eaB; bool vA, vB;
        int e = p0;
        LOADQ(uxA, eaA, vA)
        e += 4;
        while (e < p1) {
            LOADQ(uxB, eaB, vB)
            e += 4;
            COMPQ(uxA, eaA, vA)
            if (e >= p1) { COMPQ(uxB, eaB, vB) goto redux; }
            LOADQ(uxA, eaA, vA)
            e += 4;
            COMPQ(uxB, eaB, vB)
        }
        COMPQ(uxA, eaA, vA)
    }
redux:;
#undef LOADQ
#undef COMPQ

    Z += __shfl_xor(Z, 16); Z += __shfl_xor(Z, 32);
#pragma unroll
    for (int q = 0; q < 4; ++q) {
        acc2[q].x += __shfl_xor(acc2[q].x, 16);
        acc2[q].x += __shfl_xor(acc2[q].x, 32);
        acc2[q].y += __shfl_xor(acc2[q].y, 16);
        acc2[q].y += __shfl_xor(acc2[q].y, 32);
    }
    float inv = 1.f / (Z + 1e-16f);
    float acc[8] = {acc2[0].x, acc2[0].y, acc2[1].x, acc2[1].y,
                    acc2[2].x, acc2[2].y, acc2[3].x, acc2[3].y};

    // residual (bf16 h) + LN over the 128 dims held by the 16 head-lanes
    u4 uh = *(const u4*)(hb + base + dbase);
    f2 hr0 = b2f2v(uh.x), hr1 = b2f2v(uh.y), hr2 = b2f2v(uh.z), hr3 = b2f2v(uh.w);
    float hres[8] = {hr0.x, hr0.y, hr1.x, hr1.y, hr2.x, hr2.y, hr3.x, hr3.y};
    f4 gb0 = *(const f4*)(gbias + dbase), gb1 = *(const f4*)(gbias + dbase + 4);
    float gb8[8] = {gb0.x, gb0.y, gb0.z, gb0.w, gb1.x, gb1.y, gb1.z, gb1.w};
    float o[8], sm = 0.f, sq = 0.f;
#pragma unroll
    for (int q = 0; q < 8; ++q) {
        o[q] = acc[q] * inv + gb8[q] + hres[q];
        sm += o[q]; sq += o[q] * o[q];
    }
#pragma unroll
    for (int k = 1; k < 16; k <<= 1) { sm += __shfl_xor(sm, k); sq += __shfl_xor(sq, k); }
    float mu = sm * (1.f / 128.f);
    float var = sq * (1.f / 128.f) - mu * mu;
    float rinv = rsqrtf(var + 1e-5f);
    f4 g0 = *(const f4*)(g + dbase), g1 = *(const f4*)(g + dbase + 4);
    float g8[8] = {g0.x, g0.y, g0.z, g0.w, g1.x, g1.y, g1.z, g1.w};
    f4 b0 = *(const f4*)(b + dbase), b1 = *(const f4*)(b + dbase + 4);
    float b8[8] = {b0.x, b0.y, b0.z, b0.w, b1.x, b1.y, b1.z, b1.w};
    float v8[8];
#pragma unroll
    for (int q = 0; q < 8; ++q) v8[q] = (o[q] - mu) * rinv * g8[q] + b8[q];
    if (grp == 0) {
        u4 hu;
        hu.x = pk2(v8[0], v8[1]); hu.y = pk2(v8[2], v8[3]);
        hu.z = pk2(v8[4], v8[5]); hu.w = pk2(v8[6], v8[7]);
        *(u4*)(hb + base + dbase) = hu;
    }
}

// ---------------------------------------------------------------- per-store partial sums (bf16 h, no global atomics)
__global__ __launch_bounds__(256) void k_store_sum(const ushort_t* __restrict__ hb,
                                                   const int* __restrict__ mask,
                                                   float* __restrict__ psums,   // [SSB][NSTORE*HID]
                                                   int* __restrict__ pcnts) {   // [SSB][NSTORE]
    __shared__ float ls[NSTORE * HID];
    __shared__ int lc[NSTORE];
    int t = threadIdx.x, bidx = blockIdx.x;
    for (int i = t; i < NSTORE * HID; i += 256) ls[i] = 0.f;
    if (t < NSTORE) lc[t] = 0;
    __syncthreads();
    int wid = bidx * 4 + (t >> 6);
    int lane = t & 63;
    int nw = SSB * 4;
    int d0 = lane * 2;
    for (int node = wid; node < NN; node += nw) {
        int s = mask[node];
        unsigned int hv = ((const unsigned int*)(hb + (size_t)node * HID))[lane];
        f2 v = b2f2v(hv);
        atomicAdd(&ls[s * HID + d0], v.x);
        atomicAdd(&ls[s * HID + d0 + 1], v.y);
        if (lane == 0) atomicAdd(&lc[s], 1);
    }
    __syncthreads();
    for (int i = t; i < NSTORE * HID; i += 256) psums[(size_t)bidx * (NSTORE * HID) + i] = ls[i];
    if (t < NSTORE) pcnts[bidx * NSTORE + t] = lc[t];
}

// ---------------------------------------------------------------- gate (1024-thread: 8 slice-chains of 4 -> 16 latency
// rounds instead of 64)
__global__ __launch_bounds__(1024) void k_gate(const float* __restrict__ psums,
                                               const int* __restrict__ pcnts,
                                               const float* __restrict__ ctxW,
                                               const float* __restrict__ ctxb,
                                               float* __restrict__ gm) {
    __shared__ float hpart[8][HID];
    __shared__ float mloc[HID];
    __shared__ int cw16[16];
    int s = blockIdx.x, t = threadIdx.x;
    int d = t & 127, half = t >> 7;              // half 0..7
    int lane = t & 63, wv = t >> 6;
    float s0 = 0.f, s1 = 0.f, s2 = 0.f, s3 = 0.f;
    for (int b = half * 4; b < SSB; b += 32) {   // SSB/32 = 16 iterations
        s0 += psums[(size_t)(b + 0) * (NSTORE * HID) + s * HID + d];
        s1 += psums[(size_t)(b + 1) * (NSTORE * HID) + s * HID + d];
        s2 += psums[(size_t)(b + 2) * (NSTORE * HID) + s * HID + d];
        s3 += psums[(size_t)(b + 3) * (NSTORE * HID) + s * HID + d];
    }
    float sum = (s0 + s1) + (s2 + s3);
    int c = (t < SSB) ? pcnts[t * NSTORE + s] : 0;
#pragma unroll
    for (int k = 1; k < 64; k <<= 1) c += __shfl_xor(c, k);
    if (lane == 0) cw16[wv] = c;
    if (half) hpart[half][d] = sum;
    __syncthreads();
    if (half == 0) {
        float tot = sum;
#pragma unroll
        for (int h = 1; h < 8; ++h) tot += hpart[h][d];
        int ct = 0;
#pragma unroll
        for (int k = 0; k < 16; ++k) ct += cw16[k];
        float cnt = fmaxf((float)ct, 1.f);
        mloc[d] = tot / cnt;
    }
    __syncthreads();
    if (half == 0) {
        float acc = ctxb[d];
        for (int j = 0; j < HID; ++j) acc += mloc[j] * ctxW[j * HID + d];
        float gate = 1.f / (1.f + __expf(-acc));
        gm[s * HID + d] = gate * mloc[d];
    }
}

// ---------------------------------------------------------------- final: out = LN(hb + gm[store])
__global__ __launch_bounds__(256) void k_final(const ushort_t* __restrict__ hb,
                                               const int* __restrict__ mask,
                                               const float* __restrict__ gm,
                                               const float* __restrict__ g,
                                               const float* __restrict__ b,
                                               float* __restrict__ out) {
    int wid = (blockIdx.x * 256 + threadIdx.x) >> 6;
    int lane = threadIdx.x & 63;
    if (wid >= NN) return;
    size_t base = (size_t)wid * HID;
    int s = mask[wid];
    int d0 = lane * 2, d1 = d0 + 1;
    unsigned int hv = ((const unsigned int*)(hb + base))[lane];
    f2 hvv = b2f2v(hv);
    float v0 = hvv.x + gm[s * HID + d0];
    float v1 = hvv.y + gm[s * HID + d1];
    float sm = v0 + v1, sq = v0 * v0 + v1 * v1;
#pragma unroll
    for (int k = 1; k < 64; k <<= 1) { sm += __shfl_xor(sm, k); sq += __shfl_xor(sq, k); }
    float mu = sm * (1.f / 128.f);
    float var = sq * (1.f / 128.f) - mu * mu;
    float r = rsqrtf(var + 1e-5f);
    float2 ov;
    ov.x = (v0 - mu) * r * g[d0] + b[d0];
    ov.y = (v1 - mu) * r * g[d1] + b[d1];
    *(float2*)(out + base + d0) = ov;
}

// ---------------------------------------------------------------- launch
extern "C" void kernel_launch(void* const* d_in, const int* in_sizes, int n_in,
                              void* d_out, int out_size, void* d_ws, size_t ws_size,
                              hipStream_t stream) {
    const float* x      = (const float*)d_in[0];
    const int*   ei     = (const int*)d_in[1];
    const float* ew     = (const float*)d_in[2];
    const int*   smask  = (const int*)d_in[3];
    const float* inW    = (const float*)d_in[4];
    const float* inb    = (const float*)d_in[5];
    const float* ing    = (const float*)d_in[6];
    const float* inbeta = (const float*)d_in[7];
    const float* gWl    = (const float*)d_in[8];
    const float* gbl    = (const float*)d_in[9];
    const float* gWr    = (const float*)d_in[10];
    const float* gbr    = (const float*)d_in[11];
    const float* gWe    = (const float*)d_in[12];
    const float* gatt   = (const float*)d_in[13];
    const float* gbias  = (const float*)d_in[14];
    const float* blkg   = (const float*)d_in[15];
    const float* blkb   = (const float*)d_in[16];
    const float* ctxW   = (const float*)d_in[17];
    const float* ctxb   = (const float*)d_in[18];
    const float* fing   = (const float*)d_in[19];
    const float* finb   = (const float*)d_in[20];
    float* out = (float*)d_out;

    float* ws = (float*)d_ws;
    size_t o = 0;
    int2*     csr    = (int2*)(ws + o);     o += (size_t)ET * 2;
    float*    gm     = ws + o;              o += NSTORE * HID;
    int*      offs   = (int*)(ws + o);      o += 50004;
    int*      rank   = (int*)(ws + o);      o += EE;
    ushort_t* hb     = (ushort_t*)(ws + o); o += (size_t)NN * HID / 2;
    ushort_t* xlb    = (ushort_t*)(ws + o); o += (size_t)NN * HID / 2;
    ushort_t* xrb    = (ushort_t*)(ws + o); o += (size_t)NN * HID / 2;
    ushort_t* inWt   = (ushort_t*)(ws + o); o += 128 * 64 / 2;
    ushort_t* Wlt    = (ushort_t*)(ws + o); o += 3 * 128 * 128 / 2;
    ushort_t* Wrt    = (ushort_t*)(ws + o); o += 3 * 128 * 128 / 2;
    int*      bsum   = (int*)(ws + o);      o += 256;
    float*    psums  = ws + o;              o += (size_t)SSB * NSTORE * HID;
    int*      pcnts  = (int*)(ws + o);      o += SSB * NSTORE;
    u32*      packed = (u32*)(ws + o);      o += NN;
    size_t zbytes = (size_t)NN * 4;

    hipMemsetAsync((void*)packed, 0, zbytes, stream);

    const int WB = NN / 4;                    // wave-per-node kernels

    k_build<<<CNT_B + WCV_B + IWC_B, 256, 0, stream>>>(ei, ew, inW, gWl, gWr,
                                                       inWt, Wlt, Wrt, packed, rank);
    k_psum<<<NBL, 256, 0, stream>>>(packed, bsum);
    k_offs2<<<NBL, 256, 0, stream>>>(packed, bsum, offs);
    k_inproj<<<IPB, 512, 0, stream>>>(x, inWt, inb, ing, inbeta, hb);

    for (int l = 0; l < 3; ++l) {
        int nb = GEMB2 + (l == 0 ? SCT_B2 : 0);   // layer 0 carries the CSR scatter blocks
        k_gemm2<<<nb, 512, 0, stream>>>(hb, Wlt + (size_t)l * HID * HID, Wrt + (size_t)l * HID * HID,
                                        gbl + l * HID, gbr + l * HID, xlb, xrb, NN,
                                        ei, ew, offs, packed, rank, csr);
        k_attn<<<WB, 256, 0, stream>>>(xlb, xrb, hb, offs, csr,
                                       gWe + l * HID, gatt + l * HID, gbias + l * HID,
                                       blkg + l * HID, blkb + l * HID);
    }

    k_store_sum<<<SSB, 256, 0, stream>>>(hb, smask, psums, pcnts);
    k_gate<<<NSTORE, 1024, 0, stream>>>(psums, pcnts, ctxW, ctxb, gm);
    k_final<<<WB, 256, 0, stream>>>(hb, smask, gm, fing, finb, out);
}

// Round 13
// 440.839 us; speedup vs baseline: 1.0497x; 1.0497x over previous
//
#include <hip/hip_runtime.h>
#include <math.h>

#define NN 50000
#define EE 800000
#define ET (EE + NN)
#define HID 128
#define NSTORE 50
#define NBL 196                      // ceil(NN/256)
#define CNT_B 3125                   // EE/256 edge-count blocks
#define WCV_B 192                    // 3*128*128/256 weight cvt blocks
#define IWC_B 32                     // 128*64/256 inW cvt blocks
#define SCT_B2 1661                  // ceil(ET/512) scatter blocks (512-thread, in gemm2 l0)
#define GEMB 391                     // ceil(NN/128) gemm tiles (128-row, proven optimum)
#define IPB 782                      // ceil(NN/64) inproj tiles (64-row, latency-sized)
#define SSB 512                      // store-sum partial blocks (2 blocks/CU)

typedef unsigned short ushort_t;
typedef unsigned int u32;
typedef __attribute__((ext_vector_type(8))) short bf8;
typedef __attribute__((ext_vector_type(4))) float f4;
typedef __attribute__((ext_vector_type(2))) float f2;
typedef __attribute__((ext_vector_type(4))) unsigned int u4;

__device__ __forceinline__ ushort_t f2b(float f) {
    union { float f; unsigned int i; } v; v.f = f;
    unsigned int r = (v.i + 0x7fffu + ((v.i >> 16) & 1u)) >> 16;
    return (ushort_t)r;
}
__device__ __forceinline__ f2 b2f2v(unsigned int u) {
    union { unsigned int i; float f; } lo, hi;
    lo.i = u << 16; hi.i = u & 0xffff0000u;
    f2 r; r.x = lo.f; r.y = hi.f; return r;
}
__device__ __forceinline__ unsigned int pk2(float lo, float hi) {
    return (unsigned int)f2b(lo) | ((unsigned int)f2b(hi) << 16);
}
__device__ __forceinline__ f2 max2(f2 a, f2 b) {
#if __has_builtin(__builtin_elementwise_max)
    return __builtin_elementwise_max(a, b);
#else
    f2 r; r.x = fmaxf(a.x, b.x); r.y = fmaxf(a.y, b.y); return r;
#endif
}

// ---------------------------------------------------------------- build: edge count (u32 packed atomic) + weight cvt.
// packed[dst]: bits 24+: degree (<=255); bits 0..23: sum(ew) in 2^-18 fixed
// point (deg<=~50, ew<1 -> sum < 50*2^18 < 2^24: no field overflow).
__global__ __launch_bounds__(256) void k_build(const int* __restrict__ ei, const float* __restrict__ ew,
                                               const float* __restrict__ inW,
                                               const float* __restrict__ gWl, const float* __restrict__ gWr,
                                               ushort_t* __restrict__ inWt,
                                               ushort_t* __restrict__ Wlt, ushort_t* __restrict__ Wrt,
                                               u32* __restrict__ packed, int* __restrict__ rank) {
    int b = blockIdx.x, t = threadIdx.x;
    if (b < CNT_B) {                               // ---- edge count
        int i = b * 256 + t;
        int dst = ei[EE + i];
        unsigned int wfix = __float2uint_rn(ew[i] * 262144.0f);
        unsigned int old = atomicAdd(&packed[dst], (1u << 24) | wfix);
        rank[i] = (int)(old >> 24);
        return;
    }
    if (b < CNT_B + WCV_B) {                       // ---- Wlt[l][n*128+k] = W[l][k*128+n]
        int i = (b - CNT_B) * 256 + t;
        int l = i >> 14, r = i & 16383, nn2 = r >> 7, k = r & 127;
        Wlt[i] = f2b(gWl[(size_t)l * 16384 + k * 128 + nn2]);
        Wrt[i] = f2b(gWr[(size_t)l * 16384 + k * 128 + nn2]);
        return;
    }
    {                                              // ---- inWt[c*64+k] = inW[k*128+c]
        int i = (b - CNT_B - WCV_B) * 256 + t;
        int c = i >> 6, k = i & 63;
        inWt[i] = f2b(inW[k * 128 + c]);
    }
}

// per-256-chunk sums of (deg+1)
__global__ __launch_bounds__(256) void k_psum(const u32* __restrict__ packed, int* __restrict__ bsum) {
    int t = threadIdx.x, bidx = blockIdx.x;
    int i = bidx * 256 + t;
    int v = (i < NN) ? (int)(packed[i] >> 24) + 1 : 0;
#pragma unroll
    for (int d = 1; d < 64; d <<= 1) v += __shfl_xor(v, d);
    __shared__ int ws4[4];
    if ((t & 63) == 0) ws4[t >> 6] = v;
    __syncthreads();
    if (t == 0) bsum[bidx] = ws4[0] + ws4[1] + ws4[2] + ws4[3];
}

// merged scan: each block redundantly sums bsum[0..bid) (196 L2-hot ints), then local scan
__global__ __launch_bounds__(256) void k_offs2(const u32* __restrict__ packed,
                                               const int* __restrict__ bsum, int* __restrict__ offs) {
    __shared__ int bws[4];
    __shared__ int wsum4[4];
    int t = threadIdx.x, bidx = blockIdx.x;
    int i = bidx * 256 + t;
    int v = (i < NN) ? (int)(packed[i] >> 24) + 1 : 0;
    int lane = t & 63, w = t >> 6;

    // block base = sum of bsum[0..bidx)
    int bv = (t < bidx) ? bsum[t] : 0;
#pragma unroll
    for (int d = 1; d < 64; d <<= 1) bv += __shfl_xor(bv, d);
    if (lane == 0) bws[w] = bv;

    // local inclusive scan within wave
    int sc = v;
#pragma unroll
    for (int d = 1; d < 64; d <<= 1) {
        int u = __shfl_up(sc, d);
        if (lane >= d) sc += u;
    }
    if (lane == 63) wsum4[w] = sc;
    __syncthreads();
    int base = bws[0] + bws[1] + bws[2] + bws[3];
    int wo = 0;
    for (int k = 0; k < w; ++k) wo += wsum4[k];
    if (i < NN) offs[i] = base + wo + sc - v;
    if (bidx == 0 && t == 0) offs[NN] = ET;
}

// ---------------------------------------------------------------- input proj: GELU + LN fused, K=64, f32 in (inline bf16 cvt).
// Latency-sized: 64-row tiles x 8 waves (4 row-groups x 2 col-halves).
__global__ __launch_bounds__(512) void k_inproj(const float* __restrict__ X,
                                                const ushort_t* __restrict__ Wt,
                                                const float* __restrict__ bias,
                                                const float* __restrict__ g,
                                                const float* __restrict__ be,
                                                ushort_t* __restrict__ hb) {
    const int K = 64;
    __shared__ float s1[2][64], s2[2][64];
    int t = threadIdx.x;
    int w = t >> 6, lane = t & 63;
    int cw = w & 1, rw = w >> 1;           // rw 0..3: 16-row group; cw: 64-col half
    int q = lane >> 4, l16 = lane & 15;
    int row0 = blockIdx.x * 64 + rw * 16;
    int col0 = cw * 64;
    bf8 z; for (int k = 0; k < 8; ++k) z[k] = 0;

    bf8 bfr[2][4];
#pragma unroll
    for (int kk = 0; kk < 2; ++kk)
#pragma unroll
        for (int j = 0; j < 4; ++j)
            bfr[kk][j] = *(const bf8*)(Wt + (size_t)(col0 + j * 16 + l16) * K + kk * 32 + q * 8);

    f4 acc[4];
#pragma unroll
    for (int j = 0; j < 4; ++j) acc[j] = (f4)(0.f);

#pragma unroll
    for (int kk = 0; kk < 2; ++kk) {
        bf8 af;
        int r = row0 + l16;
        if (r < NN) {
            const float* xp = X + (size_t)r * K + kk * 32 + q * 8;
            f4 a = *(const f4*)xp;
            f4 c = *(const f4*)(xp + 4);
            u4 up; up.x = pk2(a.x, a.y); up.y = pk2(a.z, a.w);
            up.z = pk2(c.x, c.y); up.w = pk2(c.z, c.w);
            af = *(bf8*)&up;
        } else af = z;
#pragma unroll
        for (int j = 0; j < 4; ++j)
            acc[j] = __builtin_amdgcn_mfma_f32_16x16x32_bf16(af, bfr[kk][j], acc[j], 0, 0, 0);
    }
#pragma unroll
    for (int j = 0; j < 4; ++j) {
        float bv = bias[col0 + j * 16 + l16];
#pragma unroll
        for (int r = 0; r < 4; ++r) {
            float v = acc[j][r] + bv;
            v = 0.5f * v * (1.f + erff(v * 0.70710678118654752f));
            acc[j][r] = v;
        }
    }
#pragma unroll
    for (int r = 0; r < 4; ++r) {
        float sm = acc[0][r] + acc[1][r] + acc[2][r] + acc[3][r];
        float sq = acc[0][r] * acc[0][r] + acc[1][r] * acc[1][r]
                 + acc[2][r] * acc[2][r] + acc[3][r] * acc[3][r];
#pragma unroll
        for (int k = 1; k < 16; k <<= 1) { sm += __shfl_xor(sm, k); sq += __shfl_xor(sq, k); }
        if (l16 == 0) {
            int rl = rw * 16 + q * 4 + r;
            s1[cw][rl] = sm; s2[cw][rl] = sq;
        }
    }
    __syncthreads();
#pragma unroll
    for (int r = 0; r < 4; ++r) {
        int rl = rw * 16 + q * 4 + r;
        int gr = blockIdx.x * 64 + rl;
        if (gr >= NN) continue;
        float sm = s1[0][rl] + s1[1][rl];
        float sq = s2[0][rl] + s2[1][rl];
        float mu = sm * (1.f / 128.f);
        float var = sq * (1.f / 128.f) - mu * mu;
        float rinv = rsqrtf(var + 1e-5f);
#pragma unroll
        for (int j = 0; j < 4; ++j) {
            int gc = col0 + j * 16 + l16;
            float v = (acc[j][r] - mu) * rinv * g[gc] + be[gc];
            hb[(size_t)gr * HID + gc] = f2b(v);
        }
    }
}

// ---------------------------------------------------------------- fused dual GEMM (K=128), 128-row tiles (PROVEN optimum:
// beats both 64-row variants -- per-wave MFMA count / B-reuse dominates
// block-count undersubscription for this shape). One block stages the
// 128-row A tile into swizzled LDS once; 8 waves = 2 sides x 2 row x 2 col,
// bfk[4] hoisted per kk, 64 MFMA/wave. blocks >= GEMB: CSR scatter (l0).
// csr.x = BYTE offset of source row (src * 256).
__global__ __launch_bounds__(512) void k_gemm2(const ushort_t* __restrict__ A,
                                               const ushort_t* __restrict__ Wt0,
                                               const ushort_t* __restrict__ Wt1,
                                               const float* __restrict__ b0,
                                               const float* __restrict__ b1,
                                               ushort_t* __restrict__ o0,
                                               ushort_t* __restrict__ o1, int n,
                                               const int* __restrict__ ei,
                                               const float* __restrict__ ew,
                                               const int* __restrict__ offs,
                                               const u32* __restrict__ packed,
                                               const int* __restrict__ rank,
                                               int2* __restrict__ csr) {
    int bid = blockIdx.x;
    if (bid >= GEMB) {                             // ---- CSR scatter
        int i = (bid - GEMB) * 512 + threadIdx.x;
        if (i < EE) {
            int src = ei[i], dst = ei[EE + i];
            int pos = offs[dst] + rank[i];
            int2 v; v.x = src << 8; v.y = __float_as_int(ew[i]);
            csr[pos] = v;
        } else if (i < ET) {
            int nd = i - EE;
            u32 p = packed[nd];
            int deg = (int)(p >> 24);
            float wsf = (float)(p & 0xFFFFFFu) * (1.0f / 262144.0f);
            float la = wsf / fmaxf((float)deg, 1.0f);
            int pos = offs[nd + 1] - 1;
            int2 v; v.x = nd << 8; v.y = __float_as_int(la);
            csr[pos] = v;
        }
        return;
    }
    const int K = 128;
    __shared__ char As[128 * 256];               // 32 KB, XOR-swizzled rows
    int t = threadIdx.x;
    int row0 = bid * 128;
    bf8 z; for (int k = 0; k < 8; ++k) z[k] = 0;

    {   // stage A: thread t covers row t>>2, col-chunk (t&3)*8 .. stride 32
        int row = t >> 2, cq = t & 3;
        const ushort_t* srcp = A + (size_t)(row0 + row) * K + cq * 8;
        int swz = (row & 7) << 4;
        char* dst = As + row * 256;
        bool ok = (row0 + row) < n;
#pragma unroll
        for (int k = 0; k < 4; ++k) {
            bf8 v = ok ? *(const bf8*)(srcp + k * 32) : z;
            *(bf8*)(dst + ((k * 64 + cq * 16) ^ swz)) = v;
        }
    }
    __syncthreads();

    int w = t >> 6, lane = t & 63;
    int side = w >> 2, rw = (w >> 1) & 1, cw = w & 1;
    const ushort_t* Wt = side ? Wt1 : Wt0;
    const float* bias = side ? b1 : b0;
    ushort_t* outb = side ? o1 : o0;
    int q = lane >> 4, l16 = lane & 15;
    int col0 = cw * 64;

    f4 acc[4][4];
#pragma unroll
    for (int i = 0; i < 4; ++i)
#pragma unroll
        for (int j = 0; j < 4; ++j) acc[i][j] = (f4)(0.f);

#pragma unroll
    for (int kk = 0; kk < 4; ++kk) {
        bf8 bfk[4];
#pragma unroll
        for (int j = 0; j < 4; ++j)
            bfk[j] = *(const bf8*)(Wt + (size_t)(col0 + j * 16 + l16) * K + kk * 32 + q * 8);
        bf8 af[4];
#pragma unroll
        for (int i = 0; i < 4; ++i) {
            int r = rw * 64 + i * 16 + l16;
            af[i] = *(const bf8*)(As + r * 256 + ((kk * 64 + q * 16) ^ ((r & 7) << 4)));
        }
#pragma unroll
        for (int i = 0; i < 4; ++i)
#pragma unroll
            for (int j = 0; j < 4; ++j)
                acc[i][j] = __builtin_amdgcn_mfma_f32_16x16x32_bf16(af[i], bfk[j], acc[i][j], 0, 0, 0);
    }
#pragma unroll
    for (int i = 0; i < 4; ++i) {
        int gr0 = row0 + rw * 64 + i * 16 + q * 4;
#pragma unroll
        for (int j = 0; j < 4; ++j) {
            int gc = col0 + j * 16 + l16;
            float bv = bias[gc];
#pragma unroll
            for (int r = 0; r < 4; ++r) {
                int gr = gr0 + r;
                if (gr < n) outb[(size_t)gr * HID + gc] = f2b(acc[i][j][r] + bv);
            }
        }
    }
}

// ---------------------------------------------------------------- GATv2 attention (round-1 form: VGPR 36, ~59% occ -- the
// proven floor across 9 structural variants; pattern-limited at ~2.7 TB/s
// on the L2-miss path).
__global__ __launch_bounds__(256) void k_attn(const ushort_t* __restrict__ xl,
                                              const ushort_t* __restrict__ xr,
                                              ushort_t* __restrict__ hb,
                                              const int* __restrict__ offs,
                                              const int2* __restrict__ csr,
                                              const float* __restrict__ We,
                                              const float* __restrict__ att,
                                              const float* __restrict__ gbias,
                                              const float* __restrict__ g,
                                              const float* __restrict__ b) {
    int wid = (blockIdx.x * 256 + threadIdx.x) >> 6;
    int lane = threadIdx.x & 63;
    if (wid >= NN) return;
    int hd = lane & 15;          // head index (16 heads; DH=8 in-lane)
    int grp = lane >> 4;         // edge subgroup 0..3
    int dbase = hd * 8;
    int db2 = hd * 16;           // byte offset of this head's 8 bf16 within a row
    size_t base = (size_t)wid * HID;

    f2 xr2[4], at2[4], we2[4];
    {
        u4 uxr = *(const u4*)(xr + base + dbase);
        xr2[0] = b2f2v(uxr.x); xr2[1] = b2f2v(uxr.y);
        xr2[2] = b2f2v(uxr.z); xr2[3] = b2f2v(uxr.w);
        f4 a0 = *(const f4*)(att + dbase), a1 = *(const f4*)(att + dbase + 4);
        at2[0].x = a0.x; at2[0].y = a0.y; at2[1].x = a0.z; at2[1].y = a0.w;
        at2[2].x = a1.x; at2[2].y = a1.y; at2[3].x = a1.z; at2[3].y = a1.w;
        f4 w0 = *(const f4*)(We + dbase), w1 = *(const f4*)(We + dbase + 4);
        we2[0].x = w0.x; we2[0].y = w0.y; we2[1].x = w0.z; we2[1].y = w0.w;
        we2[2].x = w1.x; we2[2].y = w1.y; we2[3].x = w1.z; we2[3].y = w1.w;
    }
    int p0 = offs[wid], p1 = offs[wid + 1];
    float Z = 0.f;
    f2 acc2[4];
#pragma unroll
    for (int q = 0; q < 4; ++q) { acc2[q].x = 0.f; acc2[q].y = 0.f; }

    // issue csr record load (16-lane same-address broadcast) + row gather
#define LOADQ(UX, EA, VM)                                                      \
    {                                                                          \
        int ei_ = e + grp;                                                     \
        VM = (ei_ < p1);                                                       \
        int2 m2_ = csr[VM ? ei_ : (p1 - 1)];                                   \
        EA = __int_as_float(m2_.y);                                            \
        UX = *(const u4*)((const char*)xl + (unsigned)m2_.x + db2);            \
    }

#define COMPQ(UX, EA, VM)                                                      \
    {                                                                          \
        f2 x2_[4];                                                             \
        x2_[0] = b2f2v(UX.x); x2_[1] = b2f2v(UX.y);                            \
        x2_[2] = b2f2v(UX.z); x2_[3] = b2f2v(UX.w);                            \
        f2 lg2_; lg2_.x = 0.f; lg2_.y = 0.f;                                   \
        _Pragma("unroll")                                                      \
        for (int q_ = 0; q_ < 4; ++q_) {                                       \
            f2 t_ = (x2_[q_] + xr2[q_]) + EA * we2[q_];                        \
            t_ = max2(t_, t_ * 0.2f);                                          \
            lg2_ += at2[q_] * t_;                                              \
        }                                                                      \
        float w_ = VM ? __expf(lg2_.x + lg2_.y) : 0.f;                         \
        Z += w_;                                                               \
        _Pragma("unroll")                                                      \
        for (int q_ = 0; q_ < 4; ++q_) acc2[q_] += w_ * x2_[q_];               \
    }

    {
        u4 uxA, uxB; float eaA, eaB; bool vA, vB;
        int e = p0;
        LOADQ(uxA, eaA, vA)
        e += 4;
        while (e < p1) {
            LOADQ(uxB, eaB, vB)
            e += 4;
            COMPQ(uxA, eaA, vA)
            if (e >= p1) { COMPQ(uxB, eaB, vB) goto redux; }
            LOADQ(uxA, eaA, vA)
            e += 4;
            COMPQ(uxB, eaB, vB)
        }
        COMPQ(uxA, eaA, vA)
    }
redux:;
#undef LOADQ
#undef COMPQ

    Z += __shfl_xor(Z, 16); Z += __shfl_xor(Z, 32);
#pragma unroll
    for (int q = 0; q < 4; ++q) {
        acc2[q].x += __shfl_xor(acc2[q].x, 16);
        acc2[q].x += __shfl_xor(acc2[q].x, 32);
        acc2[q].y += __shfl_xor(acc2[q].y, 16);
        acc2[q].y += __shfl_xor(acc2[q].y, 32);
    }
    float inv = 1.f / (Z + 1e-16f);
    float acc[8] = {acc2[0].x, acc2[0].y, acc2[1].x, acc2[1].y,
                    acc2[2].x, acc2[2].y, acc2[3].x, acc2[3].y};

    // residual (bf16 h) + LN over the 128 dims held by the 16 head-lanes
    u4 uh = *(const u4*)(hb + base + dbase);
    f2 hr0 = b2f2v(uh.x), hr1 = b2f2v(uh.y), hr2 = b2f2v(uh.z), hr3 = b2f2v(uh.w);
    float hres[8] = {hr0.x, hr0.y, hr1.x, hr1.y, hr2.x, hr2.y, hr3.x, hr3.y};
    f4 gb0 = *(const f4*)(gbias + dbase), gb1 = *(const f4*)(gbias + dbase + 4);
    float gb8[8] = {gb0.x, gb0.y, gb0.z, gb0.w, gb1.x, gb1.y, gb1.z, gb1.w};
    float o[8], sm = 0.f, sq = 0.f;
#pragma unroll
    for (int q = 0; q < 8; ++q) {
        o[q] = acc[q] * inv + gb8[q] + hres[q];
        sm += o[q]; sq += o[q] * o[q];
    }
#pragma unroll
    for (int k = 1; k < 16; k <<= 1) { sm += __shfl_xor(sm, k); sq += __shfl_xor(sq, k); }
    float mu = sm * (1.f / 128.f);
    float var = sq * (1.f / 128.f) - mu * mu;
    float rinv = rsqrtf(var + 1e-5f);
    f4 g0 = *(const f4*)(g + dbase), g1 = *(const f4*)(g + dbase + 4);
    float g8[8] = {g0.x, g0.y, g0.z, g0.w, g1.x, g1.y, g1.z, g1.w};
    f4 b0 = *(const f4*)(b + dbase), b1 = *(const f4*)(b + dbase + 4);
    float b8[8] = {b0.x, b0.y, b0.z, b0.w, b1.x, b1.y, b1.z, b1.w};
    float v8[8];
#pragma unroll
    for (int q = 0; q < 8; ++q) v8[q] = (o[q] - mu) * rinv * g8[q] + b8[q];
    if (grp == 0) {
        u4 hu;
        hu.x = pk2(v8[0], v8[1]); hu.y = pk2(v8[2], v8[3]);
        hu.z = pk2(v8[4], v8[5]); hu.w = pk2(v8[6], v8[7]);
        *(u4*)(hb + base + dbase) = hu;
    }
}

// ---------------------------------------------------------------- per-store partial sums (bf16 h, no global atomics)
__global__ __launch_bounds__(256) void k_store_sum(const ushort_t* __restrict__ hb,
                                                   const int* __restrict__ mask,
                                                   float* __restrict__ psums,   // [SSB][NSTORE*HID]
                                                   int* __restrict__ pcnts) {   // [SSB][NSTORE]
    __shared__ float ls[NSTORE * HID];
    __shared__ int lc[NSTORE];
    int t = threadIdx.x, bidx = blockIdx.x;
    for (int i = t; i < NSTORE * HID; i += 256) ls[i] = 0.f;
    if (t < NSTORE) lc[t] = 0;
    __syncthreads();
    int wid = bidx * 4 + (t >> 6);
    int lane = t & 63;
    int nw = SSB * 4;
    int d0 = lane * 2;
    for (int node = wid; node < NN; node += nw) {
        int s = mask[node];
        unsigned int hv = ((const unsigned int*)(hb + (size_t)node * HID))[lane];
        f2 v = b2f2v(hv);
        atomicAdd(&ls[s * HID + d0], v.x);
        atomicAdd(&ls[s * HID + d0 + 1], v.y);
        if (lane == 0) atomicAdd(&lc[s], 1);
    }
    __syncthreads();
    for (int i = t; i < NSTORE * HID; i += 256) psums[(size_t)bidx * (NSTORE * HID) + i] = ls[i];
    if (t < NSTORE) pcnts[bidx * NSTORE + t] = lc[t];
}

// ---------------------------------------------------------------- gate (1024-thread: 8 slice-chains of 4 -> 16 latency
// rounds instead of 64)
__global__ __launch_bounds__(1024) void k_gate(const float* __restrict__ psums,
                                               const int* __restrict__ pcnts,
                                               const float* __restrict__ ctxW,
                                               const float* __restrict__ ctxb,
                                               float* __restrict__ gm) {
    __shared__ float hpart[8][HID];
    __shared__ float mloc[HID];
    __shared__ int cw16[16];
    int s = blockIdx.x, t = threadIdx.x;
    int d = t & 127, half = t >> 7;              // half 0..7
    int lane = t & 63, wv = t >> 6;
    float s0 = 0.f, s1 = 0.f, s2 = 0.f, s3 = 0.f;
    for (int b = half * 4; b < SSB; b += 32) {   // SSB/32 = 16 iterations
        s0 += psums[(size_t)(b + 0) * (NSTORE * HID) + s * HID + d];
        s1 += psums[(size_t)(b + 1) * (NSTORE * HID) + s * HID + d];
        s2 += psums[(size_t)(b + 2) * (NSTORE * HID) + s * HID + d];
        s3 += psums[(size_t)(b + 3) * (NSTORE * HID) + s * HID + d];
    }
    float sum = (s0 + s1) + (s2 + s3);
    int c = (t < SSB) ? pcnts[t * NSTORE + s] : 0;
#pragma unroll
    for (int k = 1; k < 64; k <<= 1) c += __shfl_xor(c, k);
    if (lane == 0) cw16[wv] = c;
    if (half) hpart[half][d] = sum;
    __syncthreads();
    if (half == 0) {
        float tot = sum;
#pragma unroll
        for (int h = 1; h < 8; ++h) tot += hpart[h][d];
        int ct = 0;
#pragma unroll
        for (int k = 0; k < 16; ++k) ct += cw16[k];
        float cnt = fmaxf((float)ct, 1.f);
        mloc[d] = tot / cnt;
    }
    __syncthreads();
    if (half == 0) {
        float acc = ctxb[d];
        for (int j = 0; j < HID; ++j) acc += mloc[j] * ctxW[j * HID + d];
        float gate = 1.f / (1.f + __expf(-acc));
        gm[s * HID + d] = gate * mloc[d];
    }
}

// ---------------------------------------------------------------- final: out = LN(hb + gm[store])
__global__ __launch_bounds__(256) void k_final(const ushort_t* __restrict__ hb,
                                               const int* __restrict__ mask,
                                               const float* __restrict__ gm,
                                               const float* __restrict__ g,
                                               const float* __restrict__ b,
                                               float* __restrict__ out) {
    int wid = (blockIdx.x * 256 + threadIdx.x) >> 6;
    int lane = threadIdx.x & 63;
    if (wid >= NN) return;
    size_t base = (size_t)wid * HID;
    int s = mask[wid];
    int d0 = lane * 2, d1 = d0 + 1;
    unsigned int hv = ((const unsigned int*)(hb + base))[lane];
    f2 hvv = b2f2v(hv);
    float v0 = hvv.x + gm[s * HID + d0];
    float v1 = hvv.y + gm[s * HID + d1];
    float sm = v0 + v1, sq = v0 * v0 + v1 * v1;
#pragma unroll
    for (int k = 1; k < 64; k <<= 1) { sm += __shfl_xor(sm, k); sq += __shfl_xor(sq, k); }
    float mu = sm * (1.f / 128.f);
    float var = sq * (1.f / 128.f) - mu * mu;
    float r = rsqrtf(var + 1e-5f);
    float2 ov;
    ov.x = (v0 - mu) * r * g[d0] + b[d0];
    ov.y = (v1 - mu) * r * g[d1] + b[d1];
    *(float2*)(out + base + d0) = ov;
}

// ---------------------------------------------------------------- launch
extern "C" void kernel_launch(void* const* d_in, const int* in_sizes, int n_in,
                              void* d_out, int out_size, void* d_ws, size_t ws_size,
                              hipStream_t stream) {
    const float* x      = (const float*)d_in[0];
    const int*   ei     = (const int*)d_in[1];
    const float* ew     = (const float*)d_in[2];
    const int*   smask  = (const int*)d_in[3];
    const float* inW    = (const float*)d_in[4];
    const float* inb    = (const float*)d_in[5];
    const float* ing    = (const float*)d_in[6];
    const float* inbeta = (const float*)d_in[7];
    const float* gWl    = (const float*)d_in[8];
    const float* gbl    = (const float*)d_in[9];
    const float* gWr    = (const float*)d_in[10];
    const float* gbr    = (const float*)d_in[11];
    const float* gWe    = (const float*)d_in[12];
    const float* gatt   = (const float*)d_in[13];
    const float* gbias  = (const float*)d_in[14];
    const float* blkg   = (const float*)d_in[15];
    const float* blkb   = (const float*)d_in[16];
    const float* ctxW   = (const float*)d_in[17];
    const float* ctxb   = (const float*)d_in[18];
    const float* fing   = (const float*)d_in[19];
    const float* finb   = (const float*)d_in[20];
    float* out = (float*)d_out;

    float* ws = (float*)d_ws;
    size_t o = 0;
    int2*     csr    = (int2*)(ws + o);     o += (size_t)ET * 2;
    float*    gm     = ws + o;              o += NSTORE * HID;
    int*      offs   = (int*)(ws + o);      o += 50004;
    int*      rank   = (int*)(ws + o);      o += EE;
    ushort_t* hb     = (ushort_t*)(ws + o); o += (size_t)NN * HID / 2;
    ushort_t* xlb    = (ushort_t*)(ws + o); o += (size_t)NN * HID / 2;
    ushort_t* xrb    = (ushort_t*)(ws + o); o += (size_t)NN * HID / 2;
    ushort_t* inWt   = (ushort_t*)(ws + o); o += 128 * 64 / 2;
    ushort_t* Wlt    = (ushort_t*)(ws + o); o += 3 * 128 * 128 / 2;
    ushort_t* Wrt    = (ushort_t*)(ws + o); o += 3 * 128 * 128 / 2;
    int*      bsum   = (int*)(ws + o);      o += 256;
    float*    psums  = ws + o;              o += (size_t)SSB * NSTORE * HID;
    int*      pcnts  = (int*)(ws + o);      o += SSB * NSTORE;
    u32*      packed = (u32*)(ws + o);      o += NN;
    size_t zbytes = (size_t)NN * 4;

    hipMemsetAsync((void*)packed, 0, zbytes, stream);

    const int WB = NN / 4;                    // wave-per-node kernels

    k_build<<<CNT_B + WCV_B + IWC_B, 256, 0, stream>>>(ei, ew, inW, gWl, gWr,
                                                       inWt, Wlt, Wrt, packed, rank);
    k_psum<<<NBL, 256, 0, stream>>>(packed, bsum);
    k_offs2<<<NBL, 256, 0, stream>>>(packed, bsum, offs);
    k_inproj<<<IPB, 512, 0, stream>>>(x, inWt, inb, ing, inbeta, hb);

    for (int l = 0; l < 3; ++l) {
        int nb = GEMB + (l == 0 ? SCT_B2 : 0);   // layer 0 carries the CSR scatter blocks
        k_gemm2<<<nb, 512, 0, stream>>>(hb, Wlt + (size_t)l * HID * HID, Wrt + (size_t)l * HID * HID,
                                        gbl + l * HID, gbr + l * HID, xlb, xrb, NN,
                                        ei, ew, offs, packed, rank, csr);
        k_attn<<<WB, 256, 0, stream>>>(xlb, xrb, hb, offs, csr,
                                       gWe + l * HID, gatt + l * HID, gbias + l * HID,
                                       blkg + l * HID, blkb + l * HID);
    }

    k_store_sum<<<SSB, 256, 0, stream>>>(hb, smask, psums, pcnts);
    k_gate<<<NSTORE, 1024, 0, stream>>>(psums, pcnts, ctxW, ctxb, gm);
    k_final<<<WB, 256, 0, stream>>>(hb, smask, gm, fing, finb, out);
}